// Round 9
// baseline (78.438 us; speedup 1.0000x reference)
//
#include <hip/hip_runtime.h>
#include <hip/hip_bf16.h>
#include <math.h>

#define DV 256
#define NH 8
#define NB 4
#define NQ 2048
#define NKK 2048

typedef __attribute__((ext_vector_type(8))) short s8v;
typedef __attribute__((ext_vector_type(16))) float fx16;

typedef const __attribute__((address_space(1))) char g1c;
typedef __attribute__((address_space(3))) char l3c;

__device__ __forceinline__ void gl_lds16(const void* g, void* l) {
    __builtin_amdgcn_global_load_lds((g1c*)g, (l3c*)l, 16, 0, 0);
}
__device__ __forceinline__ unsigned cvtpk_bf16(float lo, float hi) {
    unsigned r;
    asm("v_cvt_pk_bf16_f32 %0, %1, %2" : "=v"(r) : "v"(lo), "v"(hi));
    return r;
}
__device__ __forceinline__ ushort f2bf(float x) {
    unsigned u = __builtin_bit_cast(unsigned, x);
    return (ushort)((u + 0x7fffu + ((u >> 16) & 1u)) >> 16);
}
__device__ __forceinline__ float bf2f(ushort h) {
    return __builtin_bit_cast(float, (unsigned)h << 16);
}

// ---------------- weight prep: W* f32 -> fragment-order bf16 (0.5 MB out) ----------------
__global__ __launch_bounds__(256) void prep_w_k(
    const float* __restrict__ Wq, const float* __restrict__ Wk,
    const float* __restrict__ Wv, const float* __restrict__ Wo,
    ushort* __restrict__ Wf)
{
    const int j = blockIdx.x * 256 + threadIdx.x;       // 0..32767 chunks
    const int w = j >> 13, c = j & 8191;
    const int bn = c >> 11, s = (c >> 8) & 7, cc = c & 255;
    const int colblk = cc >> 7, ks = (cc >> 6) & 1, g5w = (cc >> 5) & 1, l31w = cc & 31;
    const int col = bn * 64 + colblk * 32 + l31w;
    const int k = s * 32 + ks * 16 + g5w * 8;
    const float* Wsrc = (w == 0) ? Wq : (w == 1) ? Wk : (w == 2) ? Wv : Wo;
    const float* src = Wsrc + (size_t)col * 256 + k;
    float4 a = *(const float4*)src;
    float4 b = *(const float4*)(src + 4);
    uint4 pk;
    pk.x = cvtpk_bf16(a.x, a.y); pk.y = cvtpk_bf16(a.z, a.w);
    pk.z = cvtpk_bf16(b.x, b.y); pk.w = cvtpk_bf16(b.z, b.w);
    *(uint4*)(Wf + (size_t)j * 8) = pk;
}

// ---------------- fused Q/K/V projections, f32 A staged directly ----------------
// BM=128, BN=64, BK=32, 4 waves. A staged f32 (32B/chunk), converted to bf16 fragments
// at LDS-read time (RNE, same as a separate prep pass). Wave wv owns rows wv*32..+31.
__global__ __launch_bounds__(256) void gemm_qkv_k(
    const float* __restrict__ Qf, const float* __restrict__ Kf,
    const ushort* __restrict__ Wf,
    const float* __restrict__ bq, const float* __restrict__ bk, const float* __restrict__ bv,
    ushort* __restrict__ Qb, ushort* __restrict__ Kb, ushort* __restrict__ Vt)
{
    __shared__ __align__(16) char lds[2][20480];   // A f32 16KB + W bf16 4KB per buffer
    const int t = threadIdx.x, lane = t & 63, wv = t >> 6;
    const int l31 = lane & 31, g5 = lane >> 5;
    const int bm = blockIdx.x, bn = blockIdx.y;
    const int z = blockIdx.z;
    const float* Af = (z == 0) ? Qf : Kf;
    const ushort* WF = Wf + (size_t)z * 65536;
    const float* bias = (z == 0) ? bq : (z == 1) ? bk : bv;

    // A part q = k*256 + t: chunk c = q>>1, half p = q&1
    int arow[4], aoff[4];
#pragma unroll
    for (int k = 0; k < 4; ++k) {
        const int q = k * 256 + t, c = q >> 1, p = q & 1;
        arow[k] = bm * 128 + (c >> 7) * 32 + (c & 31);
        aoff[k] = ((c >> 6) & 1) * 16 + ((c >> 5) & 1) * 8 + p * 4;
    }
    const ushort* wsrc = WF + (size_t)(bn * 8) * 2048 + t * 8;

#pragma unroll
    for (int k = 0; k < 4; ++k)
        gl_lds16(Af + (size_t)arow[k] * 256 + aoff[k],
                 &lds[0][k * 4096 + wv * 1024 + lane * 16]);
    gl_lds16(wsrc, &lds[0][16384 + wv * 1024 + lane * 16]);
    __syncthreads();

    fx16 acc0 = {}, acc1 = {};
    for (int s = 0; s < 8; ++s) {
        const int buf = s & 1;
        if (s + 1 < 8) {
#pragma unroll
            for (int k = 0; k < 4; ++k)
                gl_lds16(Af + (size_t)arow[k] * 256 + (s + 1) * 32 + aoff[k],
                         &lds[buf ^ 1][k * 4096 + wv * 1024 + lane * 16]);
            gl_lds16(wsrc + (s + 1) * 2048, &lds[buf ^ 1][16384 + wv * 1024 + lane * 16]);
        }
        const char* Al = lds[buf];
        const char* Wl = lds[buf] + 16384;
        float4 fa0 = *(const float4*)(Al + (wv * 2 + 0) * 2048 + lane * 32);
        float4 fb0 = *(const float4*)(Al + (wv * 2 + 0) * 2048 + lane * 32 + 16);
        float4 fa1 = *(const float4*)(Al + (wv * 2 + 1) * 2048 + lane * 32);
        float4 fb1 = *(const float4*)(Al + (wv * 2 + 1) * 2048 + lane * 32 + 16);
        union { unsigned u[4]; s8v v; } A0, A1;
        A0.u[0] = cvtpk_bf16(fa0.x, fa0.y); A0.u[1] = cvtpk_bf16(fa0.z, fa0.w);
        A0.u[2] = cvtpk_bf16(fb0.x, fb0.y); A0.u[3] = cvtpk_bf16(fb0.z, fb0.w);
        A1.u[0] = cvtpk_bf16(fa1.x, fa1.y); A1.u[1] = cvtpk_bf16(fa1.z, fa1.w);
        A1.u[2] = cvtpk_bf16(fb1.x, fb1.y); A1.u[3] = cvtpk_bf16(fb1.z, fb1.w);
        s8v b00 = *(const s8v*)(Wl + 0 * 1024 + lane * 16);
        s8v b01 = *(const s8v*)(Wl + 1 * 1024 + lane * 16);
        s8v b10 = *(const s8v*)(Wl + 2 * 1024 + lane * 16);
        s8v b11 = *(const s8v*)(Wl + 3 * 1024 + lane * 16);
        __builtin_amdgcn_s_setprio(1);
        acc0 = __builtin_amdgcn_mfma_f32_32x32x16_bf16(A0.v, b00, acc0, 0, 0, 0);
        acc0 = __builtin_amdgcn_mfma_f32_32x32x16_bf16(A1.v, b01, acc0, 0, 0, 0);
        acc1 = __builtin_amdgcn_mfma_f32_32x32x16_bf16(A0.v, b10, acc1, 0, 0, 0);
        acc1 = __builtin_amdgcn_mfma_f32_32x32x16_bf16(A1.v, b11, acc1, 0, 0, 0);
        __builtin_amdgcn_s_setprio(0);
        __syncthreads();
    }

    const int row_b = bm * 128 + wv * 32;
    const float CE = 0.17677669529663687f * 1.4426950408889634f; // (1/sqrt(32))*log2(e)
    const float bs0 = bias[bn * 64 + l31];
    const float bs1 = bias[bn * 64 + 32 + l31];
    if (z == 0) {
#pragma unroll
        for (int r = 0; r < 16; ++r) {
            const int row_g = row_b + (r & 3) + 8 * (r >> 2) + 4 * g5;
            Qb[(size_t)row_g * 256 + bn * 64 + l31]      = f2bf((acc0[r] + bs0) * CE);
            Qb[(size_t)row_g * 256 + bn * 64 + 32 + l31] = f2bf((acc1[r] + bs1) * CE);
        }
    } else if (z == 1) {
#pragma unroll
        for (int r = 0; r < 16; ++r) {
            const int row_g = row_b + (r & 3) + 8 * (r >> 2) + 4 * g5;
            Kb[(size_t)row_g * 256 + bn * 64 + l31]      = f2bf(acc0[r] + bs0);
            Kb[(size_t)row_g * 256 + bn * 64 + 32 + l31] = f2bf(acc1[r] + bs1);
        }
    } else {
#pragma unroll
        for (int r = 0; r < 16; ++r) {
            const int row_g = row_b + (r & 3) + 8 * (r >> 2) + 4 * g5;
            const int bb = row_g >> 11, n = row_g & 2047;
            Vt[((size_t)(bb * 8 + bn * 2 + 0) * 32 + l31) * 2048 + n] = f2bf(acc0[r] + bs0);
            Vt[((size_t)(bb * 8 + bn * 2 + 1) * 32 + l31) * 2048 + n] = f2bf(acc1[r] + bs1);
        }
    }
}

// ---------------- flash attention, KV-split 2x, no max-subtraction, CE pre-folded ----------------
// R6-proven body: fragments PRELOADED before MFMA clusters (no mid-cluster reloads),
// no launch_bounds min-wave forcing. l via ones-MFMA. Partial O stored bf16.
__global__ __launch_bounds__(256) void flash_mfma_k(
    const ushort* __restrict__ Qb, const ushort* __restrict__ Kb,
    const ushort* __restrict__ Vt, ushort* __restrict__ Osb, float* __restrict__ L)
{
    __shared__ __align__(16) char lds[2][8192];
    const int t = threadIdx.x;
    const int lane = t & 63, wv = t >> 6;
    const int l31 = lane & 31, g5 = lane >> 5;
    const int qt = blockIdx.x, h = blockIdx.y;
    const int b = blockIdx.z >> 1, sp = blockIdx.z & 1;

    s8v qf0, qf1;
    {
        const ushort* qp = Qb + (((size_t)b * NQ + qt * 128 + wv * 32 + l31) << 8) + h * 32 + g5 * 8;
        qf0 = *(const s8v*)(qp);
        qf1 = *(const s8v*)(qp + 16);
    }
    s8v ones;
#pragma unroll
    for (int j = 0; j < 8; ++j) ones[j] = (short)0x3F80;  // bf16 1.0

    const ushort* ksrc = Kb + (((size_t)b * NKK + sp * 1024 + ((t >> 7) * 32 + (t & 31))) << 8)
                            + h * 32 + ((t >> 6) & 1) * 16 + ((t >> 5) & 1) * 8;
    const ushort* vsrc = Vt + (((size_t)(b * NH + h) * 32 + (t & 31)) << 11) + sp * 1024
                            + (t >> 6) * 16 + ((t >> 5) & 1) * 8;

    fx16 O0 = {}, lsum = {};

    gl_lds16(ksrc, &lds[0][wv * 1024]);
    gl_lds16(vsrc, &lds[0][4096 + wv * 1024]);
    __syncthreads();

    for (int kt = 0; kt < 16; ++kt) {
        const int buf = kt & 1;
        if (kt + 1 < 16) {
            gl_lds16(ksrc + (size_t)(kt + 1) * 64 * DV, &lds[buf ^ 1][wv * 1024]);
            gl_lds16(vsrc + (kt + 1) * 64, &lds[buf ^ 1][4096 + wv * 1024]);
        }
        const char* Kl = lds[buf];
        const char* Vl = lds[buf] + 4096;
        s8v kf00 = *(const s8v*)(Kl + 0 * 1024 + lane * 16);
        s8v kf01 = *(const s8v*)(Kl + 1 * 1024 + lane * 16);
        s8v kf10 = *(const s8v*)(Kl + 2 * 1024 + lane * 16);
        s8v kf11 = *(const s8v*)(Kl + 3 * 1024 + lane * 16);
        s8v vfa[4];
        vfa[0] = *(const s8v*)(Vl + 0 * 1024 + lane * 16);
        vfa[1] = *(const s8v*)(Vl + 1 * 1024 + lane * 16);
        vfa[2] = *(const s8v*)(Vl + 2 * 1024 + lane * 16);
        vfa[3] = *(const s8v*)(Vl + 3 * 1024 + lane * 16);

        fx16 z = {};
        __builtin_amdgcn_s_setprio(1);
        fx16 Sa = __builtin_amdgcn_mfma_f32_32x32x16_bf16(kf00, qf0, z, 0, 0, 0);
        Sa = __builtin_amdgcn_mfma_f32_32x32x16_bf16(kf01, qf1, Sa, 0, 0, 0);
        fx16 Sb = __builtin_amdgcn_mfma_f32_32x32x16_bf16(kf10, qf0, z, 0, 0, 0);
        Sb = __builtin_amdgcn_mfma_f32_32x32x16_bf16(kf11, qf1, Sb, 0, 0, 0);
        __builtin_amdgcn_s_setprio(0);

        // CE pre-folded into Q: S already in log2 domain
        float p[32];
#pragma unroll
        for (int i = 0; i < 16; ++i) {
            p[i]      = __builtin_amdgcn_exp2f(Sa[i]);
            p[16 + i] = __builtin_amdgcn_exp2f(Sb[i]);
        }

        __builtin_amdgcn_s_setprio(1);
#pragma unroll
        for (int kt2 = 0; kt2 < 4; ++kt2) {
            const int pb = 8 * kt2;
            auto ra = __builtin_amdgcn_permlane32_swap(
                cvtpk_bf16(p[pb + 0], p[pb + 1]), cvtpk_bf16(p[pb + 4], p[pb + 5]), false, false);
            auto rb = __builtin_amdgcn_permlane32_swap(
                cvtpk_bf16(p[pb + 2], p[pb + 3]), cvtpk_bf16(p[pb + 6], p[pb + 7]), false, false);
            union { unsigned u[4]; s8v v; } pf;
            pf.u[0] = ra[0]; pf.u[1] = rb[0]; pf.u[2] = ra[1]; pf.u[3] = rb[1];
            O0   = __builtin_amdgcn_mfma_f32_32x32x16_bf16(vfa[kt2], pf.v, O0, 0, 0, 0);
            lsum = __builtin_amdgcn_mfma_f32_32x32x16_bf16(ones,    pf.v, lsum, 0, 0, 0);
        }
        __builtin_amdgcn_s_setprio(0);
        __syncthreads();
    }

    {
        const int qrow = qt * 128 + wv * 32 + l31;
        ushort* dst0 = Osb + (size_t)sp * (8192 * 256)
                     + (((size_t)b * NQ + qrow) << 8) + h * 32 + g5 * 4;
#pragma unroll
        for (int rr = 0; rr < 4; ++rr) {
            uint2 w;
            w.x = cvtpk_bf16(O0[4 * rr + 0], O0[4 * rr + 1]);
            w.y = cvtpk_bf16(O0[4 * rr + 2], O0[4 * rr + 3]);
            *(uint2*)(dst0 + 8 * rr) = w;
        }
        if (g5 == 0)
            L[(((size_t)sp * NB + b) * NH + h) * NQ + qrow] = lsum[0];
    }
}

// ---------------- combine 2 splits + LayerNorm0 -> bf16 ----------------
__global__ __launch_bounds__(256) void comb_ln_k(
    const ushort* __restrict__ Osb, const float* __restrict__ L,
    const float* __restrict__ g, const float* __restrict__ bb,
    ushort* __restrict__ Yb)
{
    const int t = threadIdx.x, lane = t & 63, w = t >> 6;
    const int row = blockIdx.x * 4 + w;           // [0, 8192)
    const int b = row >> 11, q = row & 2047;
    const int h = lane >> 3;
    const size_t lbase = (((size_t)b * NH + h) * NQ + q);
    const size_t LS = (size_t)NB * NH * NQ;       // 65536
    const float inv = 1.f / (L[lbase] + L[LS + lbase]);
    const size_t SZS = (size_t)8192 * 256;
    const size_t off = (size_t)row * 256 + lane * 4;
    const ushort4 x0 = *(const ushort4*)(Osb + off);
    const ushort4 x1 = *(const ushort4*)(Osb + SZS + off);
    float4 x;
    x.x = (bf2f(x0.x) + bf2f(x1.x)) * inv;
    x.y = (bf2f(x0.y) + bf2f(x1.y)) * inv;
    x.z = (bf2f(x0.z) + bf2f(x1.z)) * inv;
    x.w = (bf2f(x0.w) + bf2f(x1.w)) * inv;
    float s  = (x.x + x.y) + (x.z + x.w);
    float sq = fmaf(x.x, x.x, fmaf(x.y, x.y, fmaf(x.z, x.z, x.w * x.w)));
    for (int off2 = 32; off2; off2 >>= 1) {
        s  += __shfl_xor(s, off2);
        sq += __shfl_xor(sq, off2);
    }
    const float mean = s * (1.f / 256.f);
    const float var  = sq * (1.f / 256.f) - mean * mean;
    const float ri   = rsqrtf(var + 1e-5f);
    const float4 gv = *(const float4*)(g + lane * 4);
    const float4 bv = *(const float4*)(bb + lane * 4);
    uint2 p;
    p.x = cvtpk_bf16((x.x - mean) * ri * gv.x + bv.x, (x.y - mean) * ri * gv.y + bv.y);
    p.y = cvtpk_bf16((x.z - mean) * ri * gv.z + bv.z, (x.w - mean) * ri * gv.w + bv.w);
    *(uint2*)(Yb + (size_t)row * 256 + lane * 4) = p;
}

// ---------------- fused tail: GEMM(Wo)+bias+ReLU+residual+LN1 ----------------
__global__ __launch_bounds__(256) void gemm_ln_k(
    const ushort* __restrict__ Ain, const ushort* __restrict__ Wfo,
    const float* __restrict__ bo, const float* __restrict__ g1,
    const float* __restrict__ b1, float* __restrict__ out)
{
    __shared__ __align__(16) char alds[32768];     // full A tile, fragment layout (bf16)
    __shared__ __align__(16) char wlds[2][16384];  // W per-k-step, dbuf
    __shared__ float red[4][64][2];
    __shared__ float par[64][2];
    const int t = threadIdx.x, lane = t & 63, wv = t >> 6;
    const int l31 = lane & 31, g5 = lane >> 5;
    const int row0 = blockIdx.x * 64;

#pragma unroll
    for (int it = 0; it < 8; ++it) {
        const int id = it * 256 + t;
        const int s = id >> 8, rem = id & 255, kc = rem >> 6, row = rem & 63;
        gl_lds16(Ain + (size_t)(row0 + row) * 256 + s * 32 + (kc >> 1) * 16 + (kc & 1) * 8,
                 &alds[id * 16]);
    }
#pragma unroll
    for (int it = 0; it < 4; ++it) {
        const int id = it * 256 + t;
        gl_lds16(Wfo + ((size_t)(id >> 8) * 2048 + (id & 255)) * 8, &wlds[0][id * 16]);
    }
    __syncthreads();

    fx16 acc[2][2] = {};
    for (int s = 0; s < 8; ++s) {
        const int buf = s & 1;
        if (s + 1 < 8) {
#pragma unroll
            for (int it = 0; it < 4; ++it) {
                const int id = it * 256 + t;
                gl_lds16(Wfo + ((size_t)(id >> 8) * 2048 + (s + 1) * 256 + (id & 255)) * 8,
                         &wlds[buf ^ 1][id * 16]);
            }
        }
        s8v a[2][2], bf[2][2];
#pragma unroll
        for (int rb = 0; rb < 2; ++rb)
#pragma unroll
            for (int ks = 0; ks < 2; ++ks)
                a[rb][ks] = *(const s8v*)(alds + ((s * 4 + ks * 2 + g5) * 64 + rb * 32 + l31) * 16);
#pragma unroll
        for (int ks = 0; ks < 2; ++ks)
#pragma unroll
            for (int ch = 0; ch < 2; ++ch)
                bf[ks][ch] = *(const s8v*)(wlds[buf] + (wv * 256 + ch * 128 + ks * 64 + g5 * 32 + l31) * 16);
        __builtin_amdgcn_s_setprio(1);
#pragma unroll
        for (int rb = 0; rb < 2; ++rb)
#pragma unroll
            for (int ch = 0; ch < 2; ++ch) {
                acc[rb][ch] = __builtin_amdgcn_mfma_f32_32x32x16_bf16(a[rb][0], bf[0][ch], acc[rb][ch], 0, 0, 0);
                acc[rb][ch] = __builtin_amdgcn_mfma_f32_32x32x16_bf16(a[rb][1], bf[1][ch], acc[rb][ch], 0, 0, 0);
            }
        __builtin_amdgcn_s_setprio(0);
        __syncthreads();
    }

    const int cg0 = wv * 64 + l31, cg1 = cg0 + 32;
    const float bo0 = bo[cg0], bo1 = bo[cg1];
    const int s0 = cg0 >> 5, kk0 = cg0 & 31;
    const int s1 = cg1 >> 5, kk1 = cg1 & 31;
    const int coff0 = (s0 * 4 + ((kk0 >> 4) << 1) + ((kk0 >> 3) & 1)) * 64;
    const int coff1 = (s1 * 4 + ((kk1 >> 4) << 1) + ((kk1 >> 3) & 1)) * 64;
    float x[2][2][16];
#pragma unroll
    for (int rb = 0; rb < 2; ++rb) {
#pragma unroll
        for (int r = 0; r < 16; ++r) {
            const int row = rb * 32 + (r & 3) + 8 * (r >> 2) + 4 * g5;
            const ushort h0v = *(const ushort*)(alds + ((coff0 + row) << 4) + (kk0 & 7) * 2);
            const ushort h1v = *(const ushort*)(alds + ((coff1 + row) << 4) + (kk1 & 7) * 2);
            const float x0 = bf2f(h0v) + fmaxf(acc[rb][0][r] + bo0, 0.f);
            const float x1 = bf2f(h1v) + fmaxf(acc[rb][1][r] + bo1, 0.f);
            x[rb][0][r] = x0; x[rb][1][r] = x1;
            float sv = x0 + x1;
            float sq = fmaf(x0, x0, x1 * x1);
#pragma unroll
            for (int off = 1; off < 32; off <<= 1) {
                sv += __shfl_xor(sv, off);
                sq += __shfl_xor(sq, off);
            }
            if (l31 == 0) { red[wv][row][0] = sv; red[wv][row][1] = sq; }
        }
    }
    __syncthreads();
    if (t < 64) {
        const float sv = (red[0][t][0] + red[1][t][0]) + (red[2][t][0] + red[3][t][0]);
        const float sq = (red[0][t][1] + red[1][t][1]) + (red[2][t][1] + red[3][t][1]);
        const float mean = sv * (1.f / 256.f);
        const float var  = sq * (1.f / 256.f) - mean * mean;
        par[t][0] = mean;
        par[t][1] = rsqrtf(var + 1e-5f);
    }
    __syncthreads();
    const float g1a = g1[cg0], g1b = g1[cg1];
    const float b1a = b1[cg0], b1b = b1[cg1];
#pragma unroll
    for (int rb = 0; rb < 2; ++rb) {
#pragma unroll
        for (int r = 0; r < 16; ++r) {
            const int row = rb * 32 + (r & 3) + 8 * (r >> 2) + 4 * g5;
            const float mean = par[row][0], ri = par[row][1];
            out[(size_t)(row0 + row) * 256 + cg0] = (x[rb][0][r] - mean) * ri * g1a + b1a;
            out[(size_t)(row0 + row) * 256 + cg1] = (x[rb][1][r] - mean) * ri * g1b + b1b;
        }
    }
}

extern "C" void kernel_launch(void* const* d_in, const int* in_sizes, int n_in,
                              void* d_out, int out_size, void* d_ws, size_t ws_size,
                              hipStream_t stream) {
    const float* Q  = (const float*)d_in[0];
    const float* K  = (const float*)d_in[1];
    const float* Wq = (const float*)d_in[2];
    const float* bq = (const float*)d_in[3];
    const float* Wk = (const float*)d_in[4];
    const float* bk = (const float*)d_in[5];
    const float* Wv = (const float*)d_in[6];
    const float* bv = (const float*)d_in[7];
    const float* Wo = (const float*)d_in[8];
    const float* bo = (const float*)d_in[9];
    const float* g0 = (const float*)d_in[10];
    const float* b0 = (const float*)d_in[11];
    const float* g1 = (const float*)d_in[12];
    const float* b1 = (const float*)d_in[13];
    float* out = (float*)d_out;

    char* wsb = (char*)d_ws;
    const size_t MB = 1u << 20;
    // Layout (peak 22 MB):
    //  Qb[0,4) Kb[4,8) Vt[8,12) Wf[12,13) Osb[13,21) L[21,22) h0b[8,12) (over Vt, dead)
    ushort* Wf  = (ushort*)(wsb + 12 * MB);
    ushort* Qb  = (ushort*)(wsb + 0 * MB);
    ushort* Kb  = (ushort*)(wsb + 4 * MB);
    ushort* Vt  = (ushort*)(wsb + 8 * MB);
    ushort* Osb = (ushort*)(wsb + 13 * MB);   // 2 splits x 4 MB
    float*  L   = (float*)(wsb + 21 * MB);
    ushort* h0b = (ushort*)(wsb + 8 * MB);

    prep_w_k<<<128, 256, 0, stream>>>(Wq, Wk, Wv, Wo, Wf);
    gemm_qkv_k<<<dim3(64, 4, 3), 256, 0, stream>>>(Q, K, Wf, bq, bk, bv, Qb, Kb, Vt);
    flash_mfma_k<<<dim3(16, 8, 8), 256, 0, stream>>>(Qb, Kb, Vt, Osb, L);
    comb_ln_k<<<2048, 256, 0, stream>>>(Osb, L, g0, b0, h0b);
    gemm_ln_k<<<128, 256, 0, stream>>>(h0b, Wf + 3 * 65536, bo, g1, b1, out);
}

// Round 10
// 72.328 us; speedup vs baseline: 1.0845x; 1.0845x over previous
//
#include <hip/hip_runtime.h>
#include <hip/hip_bf16.h>
#include <math.h>

#define DV 256
#define NH 8
#define NB 4
#define NQ 2048
#define NKK 2048

typedef __attribute__((ext_vector_type(8))) short s8v;
typedef __attribute__((ext_vector_type(16))) float fx16;

typedef const __attribute__((address_space(1))) char g1c;
typedef __attribute__((address_space(3))) char l3c;

__device__ __forceinline__ void gl_lds16(const void* g, void* l) {
    __builtin_amdgcn_global_load_lds((g1c*)g, (l3c*)l, 16, 0, 0);
}
__device__ __forceinline__ unsigned cvtpk_bf16(float lo, float hi) {
    unsigned r;
    asm("v_cvt_pk_bf16_f32 %0, %1, %2" : "=v"(r) : "v"(lo), "v"(hi));
    return r;
}
__device__ __forceinline__ ushort f2bf(float x) {
    unsigned u = __builtin_bit_cast(unsigned, x);
    return (ushort)((u + 0x7fffu + ((u >> 16) & 1u)) >> 16);
}
__device__ __forceinline__ float bf2f(ushort h) {
    return __builtin_bit_cast(float, (unsigned)h << 16);
}

// ---------------- weight prep: W* f32 -> fragment-order bf16 ----------------
__global__ __launch_bounds__(256) void prep_w_k(
    const float* __restrict__ Wq, const float* __restrict__ Wk,
    const float* __restrict__ Wv, const float* __restrict__ Wo,
    ushort* __restrict__ Wf)
{
    const int j = blockIdx.x * 256 + threadIdx.x;       // 0..32767 chunks
    const int w = j >> 13, c = j & 8191;
    const int bn = c >> 11, s = (c >> 8) & 7, cc = c & 255;
    const int colblk = cc >> 7, ks = (cc >> 6) & 1, g5w = (cc >> 5) & 1, l31w = cc & 31;
    const int col = bn * 64 + colblk * 32 + l31w;
    const int k = s * 32 + ks * 16 + g5w * 8;
    const float* Wsrc = (w == 0) ? Wq : (w == 1) ? Wk : (w == 2) ? Wv : Wo;
    const float* src = Wsrc + (size_t)col * 256 + k;
    float4 a = *(const float4*)src;
    float4 b = *(const float4*)(src + 4);
    uint4 pk;
    pk.x = cvtpk_bf16(a.x, a.y); pk.y = cvtpk_bf16(a.z, a.w);
    pk.z = cvtpk_bf16(b.x, b.y); pk.w = cvtpk_bf16(b.z, b.w);
    *(uint4*)(Wf + (size_t)j * 8) = pk;
}

// ---------------- fused Q/K/V projections, f32 A staged directly ----------------
__global__ __launch_bounds__(256) void gemm_qkv_k(
    const float* __restrict__ Qf, const float* __restrict__ Kf,
    const ushort* __restrict__ Wf,
    const float* __restrict__ bq, const float* __restrict__ bk, const float* __restrict__ bv,
    ushort* __restrict__ Qb, ushort* __restrict__ Kb, ushort* __restrict__ Vt)
{
    __shared__ __align__(16) char lds[2][20480];   // A f32 16KB + W bf16 4KB per buffer
    const int t = threadIdx.x, lane = t & 63, wv = t >> 6;
    const int l31 = lane & 31, g5 = lane >> 5;
    const int bm = blockIdx.x, bn = blockIdx.y;
    const int z = blockIdx.z;
    const float* Af = (z == 0) ? Qf : Kf;
    const ushort* WF = Wf + (size_t)z * 65536;
    const float* bias = (z == 0) ? bq : (z == 1) ? bk : bv;

    int arow[4], aoff[4];
#pragma unroll
    for (int k = 0; k < 4; ++k) {
        const int q = k * 256 + t, c = q >> 1, p = q & 1;
        arow[k] = bm * 128 + (c >> 7) * 32 + (c & 31);
        aoff[k] = ((c >> 6) & 1) * 16 + ((c >> 5) & 1) * 8 + p * 4;
    }
    const ushort* wsrc = WF + (size_t)(bn * 8) * 2048 + t * 8;

#pragma unroll
    for (int k = 0; k < 4; ++k)
        gl_lds16(Af + (size_t)arow[k] * 256 + aoff[k],
                 &lds[0][k * 4096 + wv * 1024 + lane * 16]);
    gl_lds16(wsrc, &lds[0][16384 + wv * 1024 + lane * 16]);
    __syncthreads();

    fx16 acc0 = {}, acc1 = {};
    for (int s = 0; s < 8; ++s) {
        const int buf = s & 1;
        if (s + 1 < 8) {
#pragma unroll
            for (int k = 0; k < 4; ++k)
                gl_lds16(Af + (size_t)arow[k] * 256 + (s + 1) * 32 + aoff[k],
                         &lds[buf ^ 1][k * 4096 + wv * 1024 + lane * 16]);
            gl_lds16(wsrc + (s + 1) * 2048, &lds[buf ^ 1][16384 + wv * 1024 + lane * 16]);
        }
        const char* Al = lds[buf];
        const char* Wl = lds[buf] + 16384;
        float4 fa0 = *(const float4*)(Al + (wv * 2 + 0) * 2048 + lane * 32);
        float4 fb0 = *(const float4*)(Al + (wv * 2 + 0) * 2048 + lane * 32 + 16);
        float4 fa1 = *(const float4*)(Al + (wv * 2 + 1) * 2048 + lane * 32);
        float4 fb1 = *(const float4*)(Al + (wv * 2 + 1) * 2048 + lane * 32 + 16);
        union { unsigned u[4]; s8v v; } A0, A1;
        A0.u[0] = cvtpk_bf16(fa0.x, fa0.y); A0.u[1] = cvtpk_bf16(fa0.z, fa0.w);
        A0.u[2] = cvtpk_bf16(fb0.x, fb0.y); A0.u[3] = cvtpk_bf16(fb0.z, fb0.w);
        A1.u[0] = cvtpk_bf16(fa1.x, fa1.y); A1.u[1] = cvtpk_bf16(fa1.z, fa1.w);
        A1.u[2] = cvtpk_bf16(fb1.x, fb1.y); A1.u[3] = cvtpk_bf16(fb1.z, fb1.w);
        s8v b00 = *(const s8v*)(Wl + 0 * 1024 + lane * 16);
        s8v b01 = *(const s8v*)(Wl + 1 * 1024 + lane * 16);
        s8v b10 = *(const s8v*)(Wl + 2 * 1024 + lane * 16);
        s8v b11 = *(const s8v*)(Wl + 3 * 1024 + lane * 16);
        __builtin_amdgcn_s_setprio(1);
        acc0 = __builtin_amdgcn_mfma_f32_32x32x16_bf16(A0.v, b00, acc0, 0, 0, 0);
        acc0 = __builtin_amdgcn_mfma_f32_32x32x16_bf16(A1.v, b01, acc0, 0, 0, 0);
        acc1 = __builtin_amdgcn_mfma_f32_32x32x16_bf16(A0.v, b10, acc1, 0, 0, 0);
        acc1 = __builtin_amdgcn_mfma_f32_32x32x16_bf16(A1.v, b11, acc1, 0, 0, 0);
        __builtin_amdgcn_s_setprio(0);
        __syncthreads();
    }

    const int row_b = bm * 128 + wv * 32;
    const float CE = 0.17677669529663687f * 1.4426950408889634f; // (1/sqrt(32))*log2(e)
    const float bs0 = bias[bn * 64 + l31];
    const float bs1 = bias[bn * 64 + 32 + l31];
    if (z == 0) {
#pragma unroll
        for (int r = 0; r < 16; ++r) {
            const int row_g = row_b + (r & 3) + 8 * (r >> 2) + 4 * g5;
            Qb[(size_t)row_g * 256 + bn * 64 + l31]      = f2bf((acc0[r] + bs0) * CE);
            Qb[(size_t)row_g * 256 + bn * 64 + 32 + l31] = f2bf((acc1[r] + bs1) * CE);
        }
    } else if (z == 1) {
#pragma unroll
        for (int r = 0; r < 16; ++r) {
            const int row_g = row_b + (r & 3) + 8 * (r >> 2) + 4 * g5;
            Kb[(size_t)row_g * 256 + bn * 64 + l31]      = f2bf(acc0[r] + bs0);
            Kb[(size_t)row_g * 256 + bn * 64 + 32 + l31] = f2bf(acc1[r] + bs1);
        }
    } else {
#pragma unroll
        for (int r = 0; r < 16; ++r) {
            const int row_g = row_b + (r & 3) + 8 * (r >> 2) + 4 * g5;
            const int bb = row_g >> 11, n = row_g & 2047;
            Vt[((size_t)(bb * 8 + bn * 2 + 0) * 32 + l31) * 2048 + n] = f2bf(acc0[r] + bs0);
            Vt[((size_t)(bb * 8 + bn * 2 + 1) * 32 + l31) * 2048 + n] = f2bf(acc1[r] + bs1);
        }
    }
}

// ---------------- flash attention (R9-proven body, UNCHANGED) ----------------
__global__ __launch_bounds__(256) void flash_mfma_k(
    const ushort* __restrict__ Qb, const ushort* __restrict__ Kb,
    const ushort* __restrict__ Vt, ushort* __restrict__ Osb, float* __restrict__ L)
{
    __shared__ __align__(16) char lds[2][8192];
    const int t = threadIdx.x;
    const int lane = t & 63, wv = t >> 6;
    const int l31 = lane & 31, g5 = lane >> 5;
    const int qt = blockIdx.x, h = blockIdx.y;
    const int b = blockIdx.z >> 1, sp = blockIdx.z & 1;

    s8v qf0, qf1;
    {
        const ushort* qp = Qb + (((size_t)b * NQ + qt * 128 + wv * 32 + l31) << 8) + h * 32 + g5 * 8;
        qf0 = *(const s8v*)(qp);
        qf1 = *(const s8v*)(qp + 16);
    }
    s8v ones;
#pragma unroll
    for (int j = 0; j < 8; ++j) ones[j] = (short)0x3F80;  // bf16 1.0

    const ushort* ksrc = Kb + (((size_t)b * NKK + sp * 1024 + ((t >> 7) * 32 + (t & 31))) << 8)
                            + h * 32 + ((t >> 6) & 1) * 16 + ((t >> 5) & 1) * 8;
    const ushort* vsrc = Vt + (((size_t)(b * NH + h) * 32 + (t & 31)) << 11) + sp * 1024
                            + (t >> 6) * 16 + ((t >> 5) & 1) * 8;

    fx16 O0 = {}, lsum = {};

    gl_lds16(ksrc, &lds[0][wv * 1024]);
    gl_lds16(vsrc, &lds[0][4096 + wv * 1024]);
    __syncthreads();

    for (int kt = 0; kt < 16; ++kt) {
        const int buf = kt & 1;
        if (kt + 1 < 16) {
            gl_lds16(ksrc + (size_t)(kt + 1) * 64 * DV, &lds[buf ^ 1][wv * 1024]);
            gl_lds16(vsrc + (kt + 1) * 64, &lds[buf ^ 1][4096 + wv * 1024]);
        }
        const char* Kl = lds[buf];
        const char* Vl = lds[buf] + 4096;
        s8v kf00 = *(const s8v*)(Kl + 0 * 1024 + lane * 16);
        s8v kf01 = *(const s8v*)(Kl + 1 * 1024 + lane * 16);
        s8v kf10 = *(const s8v*)(Kl + 2 * 1024 + lane * 16);
        s8v kf11 = *(const s8v*)(Kl + 3 * 1024 + lane * 16);
        s8v vfa[4];
        vfa[0] = *(const s8v*)(Vl + 0 * 1024 + lane * 16);
        vfa[1] = *(const s8v*)(Vl + 1 * 1024 + lane * 16);
        vfa[2] = *(const s8v*)(Vl + 2 * 1024 + lane * 16);
        vfa[3] = *(const s8v*)(Vl + 3 * 1024 + lane * 16);

        fx16 z = {};
        __builtin_amdgcn_s_setprio(1);
        fx16 Sa = __builtin_amdgcn_mfma_f32_32x32x16_bf16(kf00, qf0, z, 0, 0, 0);
        Sa = __builtin_amdgcn_mfma_f32_32x32x16_bf16(kf01, qf1, Sa, 0, 0, 0);
        fx16 Sb = __builtin_amdgcn_mfma_f32_32x32x16_bf16(kf10, qf0, z, 0, 0, 0);
        Sb = __builtin_amdgcn_mfma_f32_32x32x16_bf16(kf11, qf1, Sb, 0, 0, 0);
        __builtin_amdgcn_s_setprio(0);

        float p[32];
#pragma unroll
        for (int i = 0; i < 16; ++i) {
            p[i]      = __builtin_amdgcn_exp2f(Sa[i]);
            p[16 + i] = __builtin_amdgcn_exp2f(Sb[i]);
        }

        __builtin_amdgcn_s_setprio(1);
#pragma unroll
        for (int kt2 = 0; kt2 < 4; ++kt2) {
            const int pb = 8 * kt2;
            auto ra = __builtin_amdgcn_permlane32_swap(
                cvtpk_bf16(p[pb + 0], p[pb + 1]), cvtpk_bf16(p[pb + 4], p[pb + 5]), false, false);
            auto rb = __builtin_amdgcn_permlane32_swap(
                cvtpk_bf16(p[pb + 2], p[pb + 3]), cvtpk_bf16(p[pb + 6], p[pb + 7]), false, false);
            union { unsigned u[4]; s8v v; } pf;
            pf.u[0] = ra[0]; pf.u[1] = rb[0]; pf.u[2] = ra[1]; pf.u[3] = rb[1];
            O0   = __builtin_amdgcn_mfma_f32_32x32x16_bf16(vfa[kt2], pf.v, O0, 0, 0, 0);
            lsum = __builtin_amdgcn_mfma_f32_32x32x16_bf16(ones,    pf.v, lsum, 0, 0, 0);
        }
        __builtin_amdgcn_s_setprio(0);
        __syncthreads();
    }

    {
        const int qrow = qt * 128 + wv * 32 + l31;
        ushort* dst0 = Osb + (size_t)sp * (8192 * 256)
                     + (((size_t)b * NQ + qrow) << 8) + h * 32 + g5 * 4;
#pragma unroll
        for (int rr = 0; rr < 4; ++rr) {
            uint2 w;
            w.x = cvtpk_bf16(O0[4 * rr + 0], O0[4 * rr + 1]);
            w.y = cvtpk_bf16(O0[4 * rr + 2], O0[4 * rr + 3]);
            *(uint2*)(dst0 + 8 * rr) = w;
        }
        if (g5 == 0)
            L[(((size_t)sp * NB + b) * NH + h) * NQ + qrow] = lsum[0];
    }
}

// ---------------- fused tail: combine+LN0 -> GEMM(Wo)+bias+ReLU+residual+LN1 ----------------
// 32 rows x 256 cols per block, grid 256 (all CUs). Phase A writes LN0 output (bf16)
// into A-fragment LDS, which also serves as the residual source in the epilogue.
__global__ __launch_bounds__(256) void tail_fused_k(
    const ushort* __restrict__ Osb, const float* __restrict__ L,
    const ushort* __restrict__ Wfo,
    const float* __restrict__ g0, const float* __restrict__ b0,
    const float* __restrict__ bo, const float* __restrict__ g1,
    const float* __restrict__ b1, float* __restrict__ out)
{
    __shared__ __align__(16) char alds[16384];     // 32 rows x 256 ch bf16, fragment layout
    __shared__ __align__(16) char wlds[2][16384];  // W per-k-step, dbuf
    __shared__ float red[4][32][2];
    __shared__ float par[32][2];
    const int t = threadIdx.x, lane = t & 63, wv = t >> 6;
    const int l31 = lane & 31, g5 = lane >> 5;
    const int row0 = blockIdx.x * 32;

    // issue W step-0 stage first so it overlaps phase A
#pragma unroll
    for (int it = 0; it < 4; ++it) {
        const int id = it * 256 + t;
        gl_lds16(Wfo + ((size_t)(id >> 8) * 2048 + (id & 255)) * 8, &wlds[0][id * 16]);
    }

    // ---- phase A: combine 2 splits + LN0 -> alds (bf16 fragment layout) ----
    {
        const int h = lane >> 3;
        const size_t SZS = (size_t)8192 * 256;
        const size_t LS = (size_t)NB * NH * NQ;    // 65536
        // fragment position for this lane's 4 channels (c = lane*4):
        const int aid0 = ((lane >> 3) * 4 + ((lane & 7) >> 1)) * 32;  // + row
        const int abyte = (lane & 1) * 8;
        const float4 gv = *(const float4*)(g0 + lane * 4);
        const float4 bv = *(const float4*)(b0 + lane * 4);
#pragma unroll
        for (int ps = 0; ps < 8; ++ps) {
            const int row = ps * 4 + wv;           // 0..31
            const int grow = row0 + row;
            const int b = grow >> 11, q = grow & 2047;
            const size_t lbase = ((size_t)b * NH + h) * NQ + q;
            const float inv = 1.f / (L[lbase] + L[LS + lbase]);
            const size_t off = (size_t)grow * 256 + lane * 4;
            const ushort4 x0 = *(const ushort4*)(Osb + off);
            const ushort4 x1 = *(const ushort4*)(Osb + SZS + off);
            float4 x;
            x.x = (bf2f(x0.x) + bf2f(x1.x)) * inv;
            x.y = (bf2f(x0.y) + bf2f(x1.y)) * inv;
            x.z = (bf2f(x0.z) + bf2f(x1.z)) * inv;
            x.w = (bf2f(x0.w) + bf2f(x1.w)) * inv;
            float s  = (x.x + x.y) + (x.z + x.w);
            float sq = fmaf(x.x, x.x, fmaf(x.y, x.y, fmaf(x.z, x.z, x.w * x.w)));
            for (int o = 32; o; o >>= 1) {
                s  += __shfl_xor(s, o);
                sq += __shfl_xor(sq, o);
            }
            const float mean = s * (1.f / 256.f);
            const float var  = sq * (1.f / 256.f) - mean * mean;
            const float ri   = rsqrtf(var + 1e-5f);
            uint2 p;
            p.x = cvtpk_bf16((x.x - mean) * ri * gv.x + bv.x, (x.y - mean) * ri * gv.y + bv.y);
            p.y = cvtpk_bf16((x.z - mean) * ri * gv.z + bv.z, (x.w - mean) * ri * gv.w + bv.w);
            *(uint2*)(alds + (aid0 + row) * 16 + abyte) = p;
        }
    }
    __syncthreads();

    // ---- phase B: GEMM over K=256 in 8 steps ----
    fx16 acc[2] = {};
    for (int s = 0; s < 8; ++s) {
        const int buf = s & 1;
        if (s + 1 < 8) {
#pragma unroll
            for (int it = 0; it < 4; ++it) {
                const int id = it * 256 + t;
                gl_lds16(Wfo + ((size_t)(id >> 8) * 2048 + (s + 1) * 256 + (id & 255)) * 8,
                         &wlds[buf ^ 1][id * 16]);
            }
        }
        s8v a[2], bf[2][2];
#pragma unroll
        for (int ks = 0; ks < 2; ++ks)
            a[ks] = *(const s8v*)(alds + ((s * 4 + ks * 2 + g5) * 32 + l31) * 16);
#pragma unroll
        for (int ks = 0; ks < 2; ++ks)
#pragma unroll
            for (int ch = 0; ch < 2; ++ch)
                bf[ks][ch] = *(const s8v*)(wlds[buf] + (wv * 256 + ch * 128 + ks * 64 + g5 * 32 + l31) * 16);
        __builtin_amdgcn_s_setprio(1);
#pragma unroll
        for (int ch = 0; ch < 2; ++ch) {
            acc[ch] = __builtin_amdgcn_mfma_f32_32x32x16_bf16(a[0], bf[0][ch], acc[ch], 0, 0, 0);
            acc[ch] = __builtin_amdgcn_mfma_f32_32x32x16_bf16(a[1], bf[1][ch], acc[ch], 0, 0, 0);
        }
        __builtin_amdgcn_s_setprio(0);
        __syncthreads();
    }

    // ---- phase C: x = h0 + relu(t + bo); LN1 over 256 cols; f32 out ----
    const int cg0 = wv * 64 + l31, cg1 = cg0 + 32;
    const float bo0 = bo[cg0], bo1 = bo[cg1];
    const int s0 = cg0 >> 5, kk0 = cg0 & 31;
    const int s1 = cg1 >> 5, kk1 = cg1 & 31;
    const int coff0 = (s0 * 4 + ((kk0 >> 4) << 1) + ((kk0 >> 3) & 1)) * 32;
    const int coff1 = (s1 * 4 + ((kk1 >> 4) << 1) + ((kk1 >> 3) & 1)) * 32;
    float x[2][16];
#pragma unroll
    for (int r = 0; r < 16; ++r) {
        const int row = (r & 3) + 8 * (r >> 2) + 4 * g5;   // 0..31
        const ushort h0v = *(const ushort*)(alds + ((coff0 + row) << 4) + (kk0 & 7) * 2);
        const ushort h1v = *(const ushort*)(alds + ((coff1 + row) << 4) + (kk1 & 7) * 2);
        const float x0 = bf2f(h0v) + fmaxf(acc[0][r] + bo0, 0.f);
        const float x1 = bf2f(h1v) + fmaxf(acc[1][r] + bo1, 0.f);
        x[0][r] = x0; x[1][r] = x1;
        float sv = x0 + x1;
        float sq = fmaf(x0, x0, x1 * x1);
#pragma unroll
        for (int o = 1; o < 32; o <<= 1) {
            sv += __shfl_xor(sv, o);
            sq += __shfl_xor(sq, o);
        }
        if (l31 == 0) { red[wv][row][0] = sv; red[wv][row][1] = sq; }
    }
    __syncthreads();
    if (t < 32) {
        const float sv = (red[0][t][0] + red[1][t][0]) + (red[2][t][0] + red[3][t][0]);
        const float sq = (red[0][t][1] + red[1][t][1]) + (red[2][t][1] + red[3][t][1]);
        const float mean = sv * (1.f / 256.f);
        const float var  = sq * (1.f / 256.f) - mean * mean;
        par[t][0] = mean;
        par[t][1] = rsqrtf(var + 1e-5f);
    }
    __syncthreads();
    const float g1a = g1[cg0], g1b = g1[cg1];
    const float b1a = b1[cg0], b1b = b1[cg1];
#pragma unroll
    for (int r = 0; r < 16; ++r) {
        const int row = (r & 3) + 8 * (r >> 2) + 4 * g5;
        const float mean = par[row][0], ri = par[row][1];
        out[(size_t)(row0 + row) * 256 + cg0] = (x[0][r] - mean) * ri * g1a + b1a;
        out[(size_t)(row0 + row) * 256 + cg1] = (x[1][r] - mean) * ri * g1b + b1b;
    }
}

extern "C" void kernel_launch(void* const* d_in, const int* in_sizes, int n_in,
                              void* d_out, int out_size, void* d_ws, size_t ws_size,
                              hipStream_t stream) {
    const float* Q  = (const float*)d_in[0];
    const float* K  = (const float*)d_in[1];
    const float* Wq = (const float*)d_in[2];
    const float* bq = (const float*)d_in[3];
    const float* Wk = (const float*)d_in[4];
    const float* bk = (const float*)d_in[5];
    const float* Wv = (const float*)d_in[6];
    const float* bv = (const float*)d_in[7];
    const float* Wo = (const float*)d_in[8];
    const float* bo = (const float*)d_in[9];
    const float* g0 = (const float*)d_in[10];
    const float* b0 = (const float*)d_in[11];
    const float* g1 = (const float*)d_in[12];
    const float* b1 = (const float*)d_in[13];
    float* out = (float*)d_out;

    char* wsb = (char*)d_ws;
    const size_t MB = 1u << 20;
    // Layout (peak 22 MB):
    //  Qb[0,4) Kb[4,8) Vt[8,12) Wf[12,13) Osb[13,21) L[21,22)
    ushort* Wf  = (ushort*)(wsb + 12 * MB);
    ushort* Qb  = (ushort*)(wsb + 0 * MB);
    ushort* Kb  = (ushort*)(wsb + 4 * MB);
    ushort* Vt  = (ushort*)(wsb + 8 * MB);
    ushort* Osb = (ushort*)(wsb + 13 * MB);   // 2 splits x 4 MB
    float*  L   = (float*)(wsb + 21 * MB);

    prep_w_k<<<128, 256, 0, stream>>>(Wq, Wk, Wv, Wo, Wf);
    gemm_qkv_k<<<dim3(64, 4, 3), 256, 0, stream>>>(Q, K, Wf, bq, bk, bv, Qb, Kb, Vt);
    flash_mfma_k<<<dim3(16, 8, 8), 256, 0, stream>>>(Qb, Kb, Vt, Osb, L);
    tail_fused_k<<<256, 256, 0, stream>>>(Osb, L, Wf + 3 * 65536, g0, b0, bo, g1, b1, out);
}

// Round 11
// 68.964 us; speedup vs baseline: 1.1374x; 1.0488x over previous
//
#include <hip/hip_runtime.h>
#include <hip/hip_bf16.h>
#include <math.h>

#define DV 256
#define NH 8
#define NB 4
#define NQ 2048
#define NKK 2048

typedef __attribute__((ext_vector_type(8))) short s8v;
typedef __attribute__((ext_vector_type(16))) float fx16;

typedef const __attribute__((address_space(1))) char g1c;
typedef __attribute__((address_space(3))) char l3c;

__device__ __forceinline__ void gl_lds16(const void* g, void* l) {
    __builtin_amdgcn_global_load_lds((g1c*)g, (l3c*)l, 16, 0, 0);
}
__device__ __forceinline__ unsigned cvtpk_bf16(float lo, float hi) {
    unsigned r;
    asm("v_cvt_pk_bf16_f32 %0, %1, %2" : "=v"(r) : "v"(lo), "v"(hi));
    return r;
}
__device__ __forceinline__ ushort f2bf(float x) {
    unsigned u = __builtin_bit_cast(unsigned, x);
    return (ushort)((u + 0x7fffu + ((u >> 16) & 1u)) >> 16);
}
__device__ __forceinline__ float bf2f(ushort h) {
    return __builtin_bit_cast(float, (unsigned)h << 16);
}

// ---------------- weight prep: W* f32 -> fragment-order bf16 ----------------
__global__ __launch_bounds__(256) void prep_w_k(
    const float* __restrict__ Wq, const float* __restrict__ Wk,
    const float* __restrict__ Wv, const float* __restrict__ Wo,
    ushort* __restrict__ Wf)
{
    const int j = blockIdx.x * 256 + threadIdx.x;       // 0..32767 chunks
    const int w = j >> 13, c = j & 8191;
    const int bn = c >> 11, s = (c >> 8) & 7, cc = c & 255;
    const int colblk = cc >> 7, ks = (cc >> 6) & 1, g5w = (cc >> 5) & 1, l31w = cc & 31;
    const int col = bn * 64 + colblk * 32 + l31w;
    const int k = s * 32 + ks * 16 + g5w * 8;
    const float* Wsrc = (w == 0) ? Wq : (w == 1) ? Wk : (w == 2) ? Wv : Wo;
    const float* src = Wsrc + (size_t)col * 256 + k;
    float4 a = *(const float4*)src;
    float4 b = *(const float4*)(src + 4);
    uint4 pk;
    pk.x = cvtpk_bf16(a.x, a.y); pk.y = cvtpk_bf16(a.z, a.w);
    pk.z = cvtpk_bf16(b.x, b.y); pk.w = cvtpk_bf16(b.z, b.w);
    *(uint4*)(Wf + (size_t)j * 8) = pk;
}

// ---------------- fused Q/K/V projections, f32 A staged directly ----------------
__global__ __launch_bounds__(256) void gemm_qkv_k(
    const float* __restrict__ Qf, const float* __restrict__ Kf,
    const ushort* __restrict__ Wf,
    const float* __restrict__ bq, const float* __restrict__ bk, const float* __restrict__ bv,
    ushort* __restrict__ Qb, ushort* __restrict__ Kb, ushort* __restrict__ Vt)
{
    __shared__ __align__(16) char lds[2][20480];   // A f32 16KB + W bf16 4KB per buffer
    const int t = threadIdx.x, lane = t & 63, wv = t >> 6;
    const int l31 = lane & 31, g5 = lane >> 5;
    const int bm = blockIdx.x, bn = blockIdx.y;
    const int z = blockIdx.z;
    const float* Af = (z == 0) ? Qf : Kf;
    const ushort* WF = Wf + (size_t)z * 65536;
    const float* bias = (z == 0) ? bq : (z == 1) ? bk : bv;

    int arow[4], aoff[4];
#pragma unroll
    for (int k = 0; k < 4; ++k) {
        const int q = k * 256 + t, c = q >> 1, p = q & 1;
        arow[k] = bm * 128 + (c >> 7) * 32 + (c & 31);
        aoff[k] = ((c >> 6) & 1) * 16 + ((c >> 5) & 1) * 8 + p * 4;
    }
    const ushort* wsrc = WF + (size_t)(bn * 8) * 2048 + t * 8;

#pragma unroll
    for (int k = 0; k < 4; ++k)
        gl_lds16(Af + (size_t)arow[k] * 256 + aoff[k],
                 &lds[0][k * 4096 + wv * 1024 + lane * 16]);
    gl_lds16(wsrc, &lds[0][16384 + wv * 1024 + lane * 16]);
    __syncthreads();

    fx16 acc0 = {}, acc1 = {};
    for (int s = 0; s < 8; ++s) {
        const int buf = s & 1;
        if (s + 1 < 8) {
#pragma unroll
            for (int k = 0; k < 4; ++k)
                gl_lds16(Af + (size_t)arow[k] * 256 + (s + 1) * 32 + aoff[k],
                         &lds[buf ^ 1][k * 4096 + wv * 1024 + lane * 16]);
            gl_lds16(wsrc + (s + 1) * 2048, &lds[buf ^ 1][16384 + wv * 1024 + lane * 16]);
        }
        const char* Al = lds[buf];
        const char* Wl = lds[buf] + 16384;
        float4 fa0 = *(const float4*)(Al + (wv * 2 + 0) * 2048 + lane * 32);
        float4 fb0 = *(const float4*)(Al + (wv * 2 + 0) * 2048 + lane * 32 + 16);
        float4 fa1 = *(const float4*)(Al + (wv * 2 + 1) * 2048 + lane * 32);
        float4 fb1 = *(const float4*)(Al + (wv * 2 + 1) * 2048 + lane * 32 + 16);
        union { unsigned u[4]; s8v v; } A0, A1;
        A0.u[0] = cvtpk_bf16(fa0.x, fa0.y); A0.u[1] = cvtpk_bf16(fa0.z, fa0.w);
        A0.u[2] = cvtpk_bf16(fb0.x, fb0.y); A0.u[3] = cvtpk_bf16(fb0.z, fb0.w);
        A1.u[0] = cvtpk_bf16(fa1.x, fa1.y); A1.u[1] = cvtpk_bf16(fa1.z, fa1.w);
        A1.u[2] = cvtpk_bf16(fb1.x, fb1.y); A1.u[3] = cvtpk_bf16(fb1.z, fb1.w);
        s8v b00 = *(const s8v*)(Wl + 0 * 1024 + lane * 16);
        s8v b01 = *(const s8v*)(Wl + 1 * 1024 + lane * 16);
        s8v b10 = *(const s8v*)(Wl + 2 * 1024 + lane * 16);
        s8v b11 = *(const s8v*)(Wl + 3 * 1024 + lane * 16);
        __builtin_amdgcn_s_setprio(1);
        acc0 = __builtin_amdgcn_mfma_f32_32x32x16_bf16(A0.v, b00, acc0, 0, 0, 0);
        acc0 = __builtin_amdgcn_mfma_f32_32x32x16_bf16(A1.v, b01, acc0, 0, 0, 0);
        acc1 = __builtin_amdgcn_mfma_f32_32x32x16_bf16(A0.v, b10, acc1, 0, 0, 0);
        acc1 = __builtin_amdgcn_mfma_f32_32x32x16_bf16(A1.v, b11, acc1, 0, 0, 0);
        __builtin_amdgcn_s_setprio(0);
        __syncthreads();
    }

    const int row_b = bm * 128 + wv * 32;
    const float CE = 0.17677669529663687f * 1.4426950408889634f; // (1/sqrt(32))*log2(e)
    const float bs0 = bias[bn * 64 + l31];
    const float bs1 = bias[bn * 64 + 32 + l31];
    if (z == 0) {
#pragma unroll
        for (int r = 0; r < 16; ++r) {
            const int row_g = row_b + (r & 3) + 8 * (r >> 2) + 4 * g5;
            Qb[(size_t)row_g * 256 + bn * 64 + l31]      = f2bf((acc0[r] + bs0) * CE);
            Qb[(size_t)row_g * 256 + bn * 64 + 32 + l31] = f2bf((acc1[r] + bs1) * CE);
        }
    } else if (z == 1) {
#pragma unroll
        for (int r = 0; r < 16; ++r) {
            const int row_g = row_b + (r & 3) + 8 * (r >> 2) + 4 * g5;
            Kb[(size_t)row_g * 256 + bn * 64 + l31]      = f2bf(acc0[r] + bs0);
            Kb[(size_t)row_g * 256 + bn * 64 + 32 + l31] = f2bf(acc1[r] + bs1);
        }
    } else {
#pragma unroll
        for (int r = 0; r < 16; ++r) {
            const int row_g = row_b + (r & 3) + 8 * (r >> 2) + 4 * g5;
            const int bb = row_g >> 11, n = row_g & 2047;
            Vt[((size_t)(bb * 8 + bn * 2 + 0) * 32 + l31) * 2048 + n] = f2bf(acc0[r] + bs0);
            Vt[((size_t)(bb * 8 + bn * 2 + 1) * 32 + l31) * 2048 + n] = f2bf(acc1[r] + bs1);
        }
    }
}

// ---------------- flash attention: Sa/Sb split-pipeline softmax ----------------
// Same math as R9 (bit-identical per-value ops), restructured so the exp2 burst of
// one S-half overlaps the PV MFMAs of the other half. Peak live p-regs 32 -> 16.
__global__ __launch_bounds__(256) void flash_mfma_k(
    const ushort* __restrict__ Qb, const ushort* __restrict__ Kb,
    const ushort* __restrict__ Vt, ushort* __restrict__ Osb, float* __restrict__ L)
{
    __shared__ __align__(16) char lds[2][8192];
    const int t = threadIdx.x;
    const int lane = t & 63, wv = t >> 6;
    const int l31 = lane & 31, g5 = lane >> 5;
    const int qt = blockIdx.x, h = blockIdx.y;
    const int b = blockIdx.z >> 1, sp = blockIdx.z & 1;

    s8v qf0, qf1;
    {
        const ushort* qp = Qb + (((size_t)b * NQ + qt * 128 + wv * 32 + l31) << 8) + h * 32 + g5 * 8;
        qf0 = *(const s8v*)(qp);
        qf1 = *(const s8v*)(qp + 16);
    }
    s8v ones;
#pragma unroll
    for (int j = 0; j < 8; ++j) ones[j] = (short)0x3F80;  // bf16 1.0

    const ushort* ksrc = Kb + (((size_t)b * NKK + sp * 1024 + ((t >> 7) * 32 + (t & 31))) << 8)
                            + h * 32 + ((t >> 6) & 1) * 16 + ((t >> 5) & 1) * 8;
    const ushort* vsrc = Vt + (((size_t)(b * NH + h) * 32 + (t & 31)) << 11) + sp * 1024
                            + (t >> 6) * 16 + ((t >> 5) & 1) * 8;

    fx16 O0 = {}, lsum = {};

    gl_lds16(ksrc, &lds[0][wv * 1024]);
    gl_lds16(vsrc, &lds[0][4096 + wv * 1024]);
    __syncthreads();

    for (int kt = 0; kt < 16; ++kt) {
        const int buf = kt & 1;
        if (kt + 1 < 16) {
            gl_lds16(ksrc + (size_t)(kt + 1) * 64 * DV, &lds[buf ^ 1][wv * 1024]);
            gl_lds16(vsrc + (kt + 1) * 64, &lds[buf ^ 1][4096 + wv * 1024]);
        }
        const char* Kl = lds[buf];
        const char* Vl = lds[buf] + 4096;
        s8v kf00 = *(const s8v*)(Kl + 0 * 1024 + lane * 16);
        s8v kf01 = *(const s8v*)(Kl + 1 * 1024 + lane * 16);
        s8v kf10 = *(const s8v*)(Kl + 2 * 1024 + lane * 16);
        s8v kf11 = *(const s8v*)(Kl + 3 * 1024 + lane * 16);
        s8v vfa[4];
        vfa[0] = *(const s8v*)(Vl + 0 * 1024 + lane * 16);
        vfa[1] = *(const s8v*)(Vl + 1 * 1024 + lane * 16);
        vfa[2] = *(const s8v*)(Vl + 2 * 1024 + lane * 16);
        vfa[3] = *(const s8v*)(Vl + 3 * 1024 + lane * 16);

        fx16 z = {};
        __builtin_amdgcn_s_setprio(1);
        fx16 Sa = __builtin_amdgcn_mfma_f32_32x32x16_bf16(kf00, qf0, z, 0, 0, 0);
        Sa = __builtin_amdgcn_mfma_f32_32x32x16_bf16(kf01, qf1, Sa, 0, 0, 0);
        fx16 Sb = __builtin_amdgcn_mfma_f32_32x32x16_bf16(kf10, qf0, z, 0, 0, 0);
        Sb = __builtin_amdgcn_mfma_f32_32x32x16_bf16(kf11, qf1, Sb, 0, 0, 0);
        __builtin_amdgcn_s_setprio(0);

        // half A: exp2(Sa) -> PV for k-slices 0,1
        float pa[16];
#pragma unroll
        for (int i = 0; i < 16; ++i) pa[i] = __builtin_amdgcn_exp2f(Sa[i]);
#pragma unroll
        for (int kt2 = 0; kt2 < 2; ++kt2) {
            const int pb = 8 * kt2;
            auto ra = __builtin_amdgcn_permlane32_swap(
                cvtpk_bf16(pa[pb + 0], pa[pb + 1]), cvtpk_bf16(pa[pb + 4], pa[pb + 5]), false, false);
            auto rb = __builtin_amdgcn_permlane32_swap(
                cvtpk_bf16(pa[pb + 2], pa[pb + 3]), cvtpk_bf16(pa[pb + 6], pa[pb + 7]), false, false);
            union { unsigned u[4]; s8v v; } pf;
            pf.u[0] = ra[0]; pf.u[1] = rb[0]; pf.u[2] = ra[1]; pf.u[3] = rb[1];
            O0   = __builtin_amdgcn_mfma_f32_32x32x16_bf16(vfa[kt2], pf.v, O0, 0, 0, 0);
            lsum = __builtin_amdgcn_mfma_f32_32x32x16_bf16(ones,    pf.v, lsum, 0, 0, 0);
        }

        // half B: exp2(Sb) (overlaps half-A MFMAs) -> PV for k-slices 2,3
        float pb2[16];
#pragma unroll
        for (int i = 0; i < 16; ++i) pb2[i] = __builtin_amdgcn_exp2f(Sb[i]);
#pragma unroll
        for (int kt2 = 2; kt2 < 4; ++kt2) {
            const int pb = 8 * (kt2 - 2);
            auto ra = __builtin_amdgcn_permlane32_swap(
                cvtpk_bf16(pb2[pb + 0], pb2[pb + 1]), cvtpk_bf16(pb2[pb + 4], pb2[pb + 5]), false, false);
            auto rb = __builtin_amdgcn_permlane32_swap(
                cvtpk_bf16(pb2[pb + 2], pb2[pb + 3]), cvtpk_bf16(pb2[pb + 6], pb2[pb + 7]), false, false);
            union { unsigned u[4]; s8v v; } pf;
            pf.u[0] = ra[0]; pf.u[1] = rb[0]; pf.u[2] = ra[1]; pf.u[3] = rb[1];
            O0   = __builtin_amdgcn_mfma_f32_32x32x16_bf16(vfa[kt2], pf.v, O0, 0, 0, 0);
            lsum = __builtin_amdgcn_mfma_f32_32x32x16_bf16(ones,    pf.v, lsum, 0, 0, 0);
        }
        __syncthreads();
    }

    {
        const int qrow = qt * 128 + wv * 32 + l31;
        ushort* dst0 = Osb + (size_t)sp * (8192 * 256)
                     + (((size_t)b * NQ + qrow) << 8) + h * 32 + g5 * 4;
#pragma unroll
        for (int rr = 0; rr < 4; ++rr) {
            uint2 w;
            w.x = cvtpk_bf16(O0[4 * rr + 0], O0[4 * rr + 1]);
            w.y = cvtpk_bf16(O0[4 * rr + 2], O0[4 * rr + 3]);
            *(uint2*)(dst0 + 8 * rr) = w;
        }
        if (g5 == 0)
            L[(((size_t)sp * NB + b) * NH + h) * NQ + qrow] = lsum[0];
    }
}

// ---------------- fused tail: combine+LN0 -> GEMM(Wo)+bias+ReLU+residual+LN1 ----------------
__global__ __launch_bounds__(256) void tail_fused_k(
    const ushort* __restrict__ Osb, const float* __restrict__ L,
    const ushort* __restrict__ Wfo,
    const float* __restrict__ g0, const float* __restrict__ b0,
    const float* __restrict__ bo, const float* __restrict__ g1,
    const float* __restrict__ b1, float* __restrict__ out)
{
    __shared__ __align__(16) char alds[16384];     // 32 rows x 256 ch bf16, fragment layout
    __shared__ __align__(16) char wlds[2][16384];  // W per-k-step, dbuf
    __shared__ float red[4][32][2];
    __shared__ float par[32][2];
    const int t = threadIdx.x, lane = t & 63, wv = t >> 6;
    const int l31 = lane & 31, g5 = lane >> 5;
    const int row0 = blockIdx.x * 32;

#pragma unroll
    for (int it = 0; it < 4; ++it) {
        const int id = it * 256 + t;
        gl_lds16(Wfo + ((size_t)(id >> 8) * 2048 + (id & 255)) * 8, &wlds[0][id * 16]);
    }

    // ---- phase A: combine 2 splits + LN0 -> alds (bf16 fragment layout) ----
    {
        const int h = lane >> 3;
        const size_t SZS = (size_t)8192 * 256;
        const size_t LS = (size_t)NB * NH * NQ;    // 65536
        const int aid0 = ((lane >> 3) * 4 + ((lane & 7) >> 1)) * 32;  // + row
        const int abyte = (lane & 1) * 8;
        const float4 gv = *(const float4*)(g0 + lane * 4);
        const float4 bv = *(const float4*)(b0 + lane * 4);
#pragma unroll
        for (int ps = 0; ps < 8; ++ps) {
            const int row = ps * 4 + wv;           // 0..31
            const int grow = row0 + row;
            const int b = grow >> 11, q = grow & 2047;
            const size_t lbase = ((size_t)b * NH + h) * NQ + q;
            const float inv = 1.f / (L[lbase] + L[LS + lbase]);
            const size_t off = (size_t)grow * 256 + lane * 4;
            const ushort4 x0 = *(const ushort4*)(Osb + off);
            const ushort4 x1 = *(const ushort4*)(Osb + SZS + off);
            float4 x;
            x.x = (bf2f(x0.x) + bf2f(x1.x)) * inv;
            x.y = (bf2f(x0.y) + bf2f(x1.y)) * inv;
            x.z = (bf2f(x0.z) + bf2f(x1.z)) * inv;
            x.w = (bf2f(x0.w) + bf2f(x1.w)) * inv;
            float s  = (x.x + x.y) + (x.z + x.w);
            float sq = fmaf(x.x, x.x, fmaf(x.y, x.y, fmaf(x.z, x.z, x.w * x.w)));
            for (int o = 32; o; o >>= 1) {
                s  += __shfl_xor(s, o);
                sq += __shfl_xor(sq, o);
            }
            const float mean = s * (1.f / 256.f);
            const float var  = sq * (1.f / 256.f) - mean * mean;
            const float ri   = rsqrtf(var + 1e-5f);
            uint2 p;
            p.x = cvtpk_bf16((x.x - mean) * ri * gv.x + bv.x, (x.y - mean) * ri * gv.y + bv.y);
            p.y = cvtpk_bf16((x.z - mean) * ri * gv.z + bv.z, (x.w - mean) * ri * gv.w + bv.w);
            *(uint2*)(alds + (aid0 + row) * 16 + abyte) = p;
        }
    }
    __syncthreads();

    // ---- phase B: GEMM over K=256 in 8 steps ----
    fx16 acc[2] = {};
    for (int s = 0; s < 8; ++s) {
        const int buf = s & 1;
        if (s + 1 < 8) {
#pragma unroll
            for (int it = 0; it < 4; ++it) {
                const int id = it * 256 + t;
                gl_lds16(Wfo + ((size_t)(id >> 8) * 2048 + (s + 1) * 256 + (id & 255)) * 8,
                         &wlds[buf ^ 1][id * 16]);
            }
        }
        s8v a[2], bf[2][2];
#pragma unroll
        for (int ks = 0; ks < 2; ++ks)
            a[ks] = *(const s8v*)(alds + ((s * 4 + ks * 2 + g5) * 32 + l31) * 16);
#pragma unroll
        for (int ks = 0; ks < 2; ++ks)
#pragma unroll
            for (int ch = 0; ch < 2; ++ch)
                bf[ks][ch] = *(const s8v*)(wlds[buf] + (wv * 256 + ch * 128 + ks * 64 + g5 * 32 + l31) * 16);
        __builtin_amdgcn_s_setprio(1);
#pragma unroll
        for (int ch = 0; ch < 2; ++ch) {
            acc[ch] = __builtin_amdgcn_mfma_f32_32x32x16_bf16(a[0], bf[0][ch], acc[ch], 0, 0, 0);
            acc[ch] = __builtin_amdgcn_mfma_f32_32x32x16_bf16(a[1], bf[1][ch], acc[ch], 0, 0, 0);
        }
        __builtin_amdgcn_s_setprio(0);
        __syncthreads();
    }

    // ---- phase C: x = h0 + relu(t + bo); LN1 over 256 cols; f32 out ----
    const int cg0 = wv * 64 + l31, cg1 = cg0 + 32;
    const float bo0 = bo[cg0], bo1 = bo[cg1];
    const int s0 = cg0 >> 5, kk0 = cg0 & 31;
    const int s1 = cg1 >> 5, kk1 = cg1 & 31;
    const int coff0 = (s0 * 4 + ((kk0 >> 4) << 1) + ((kk0 >> 3) & 1)) * 32;
    const int coff1 = (s1 * 4 + ((kk1 >> 4) << 1) + ((kk1 >> 3) & 1)) * 32;
    float x[2][16];
#pragma unroll
    for (int r = 0; r < 16; ++r) {
        const int row = (r & 3) + 8 * (r >> 2) + 4 * g5;   // 0..31
        const ushort h0v = *(const ushort*)(alds + ((coff0 + row) << 4) + (kk0 & 7) * 2);
        const ushort h1v = *(const ushort*)(alds + ((coff1 + row) << 4) + (kk1 & 7) * 2);
        const float x0 = bf2f(h0v) + fmaxf(acc[0][r] + bo0, 0.f);
        const float x1 = bf2f(h1v) + fmaxf(acc[1][r] + bo1, 0.f);
        x[0][r] = x0; x[1][r] = x1;
        float sv = x0 + x1;
        float sq = fmaf(x0, x0, x1 * x1);
#pragma unroll
        for (int o = 1; o < 32; o <<= 1) {
            sv += __shfl_xor(sv, o);
            sq += __shfl_xor(sq, o);
        }
        if (l31 == 0) { red[wv][row][0] = sv; red[wv][row][1] = sq; }
    }
    __syncthreads();
    if (t < 32) {
        const float sv = (red[0][t][0] + red[1][t][0]) + (red[2][t][0] + red[3][t][0]);
        const float sq = (red[0][t][1] + red[1][t][1]) + (red[2][t][1] + red[3][t][1]);
        const float mean = sv * (1.f / 256.f);
        const float var  = sq * (1.f / 256.f) - mean * mean;
        par[t][0] = mean;
        par[t][1] = rsqrtf(var + 1e-5f);
    }
    __syncthreads();
    const float g1a = g1[cg0], g1b = g1[cg1];
    const float b1a = b1[cg0], b1b = b1[cg1];
#pragma unroll
    for (int r = 0; r < 16; ++r) {
        const int row = (r & 3) + 8 * (r >> 2) + 4 * g5;
        const float mean = par[row][0], ri = par[row][1];
        out[(size_t)(row0 + row) * 256 + cg0] = (x[0][r] - mean) * ri * g1a + b1a;
        out[(size_t)(row0 + row) * 256 + cg1] = (x[1][r] - mean) * ri * g1b + b1b;
    }
}

extern "C" void kernel_launch(void* const* d_in, const int* in_sizes, int n_in,
                              void* d_out, int out_size, void* d_ws, size_t ws_size,
                              hipStream_t stream) {
    const float* Q  = (const float*)d_in[0];
    const float* K  = (const float*)d_in[1];
    const float* Wq = (const float*)d_in[2];
    const float* bq = (const float*)d_in[3];
    const float* Wk = (const float*)d_in[4];
    const float* bk = (const float*)d_in[5];
    const float* Wv = (const float*)d_in[6];
    const float* bv = (const float*)d_in[7];
    const float* Wo = (const float*)d_in[8];
    const float* bo = (const float*)d_in[9];
    const float* g0 = (const float*)d_in[10];
    const float* b0 = (const float*)d_in[11];
    const float* g1 = (const float*)d_in[12];
    const float* b1 = (const float*)d_in[13];
    float* out = (float*)d_out;

    char* wsb = (char*)d_ws;
    const size_t MB = 1u << 20;
    // Layout (peak 22 MB):
    //  Qb[0,4) Kb[4,8) Vt[8,12) Wf[12,13) Osb[13,21) L[21,22)
    ushort* Wf  = (ushort*)(wsb + 12 * MB);
    ushort* Qb  = (ushort*)(wsb + 0 * MB);
    ushort* Kb  = (ushort*)(wsb + 4 * MB);
    ushort* Vt  = (ushort*)(wsb + 8 * MB);
    ushort* Osb = (ushort*)(wsb + 13 * MB);   // 2 splits x 4 MB
    float*  L   = (float*)(wsb + 21 * MB);

    prep_w_k<<<128, 256, 0, stream>>>(Wq, Wk, Wv, Wo, Wf);
    gemm_qkv_k<<<dim3(64, 4, 3), 256, 0, stream>>>(Q, K, Wf, bq, bk, bv, Qb, Kb, Vt);
    flash_mfma_k<<<dim3(16, 8, 8), 256, 0, stream>>>(Qb, Kb, Vt, Osb, L);
    tail_fused_k<<<256, 256, 0, stream>>>(Osb, L, Wf + 3 * 65536, g0, b0, bo, g1, b1, out);
}